// Round 3
// baseline (348.972 us; speedup 1.0000x reference)
//
#include <hip/hip_runtime.h>
#include <cstdint>
#include <cstddef>

#define BSZ 256
#define NN 500
#define NH 250            // nodes per half
#define D 512
#define H 16
#define KSTRIDE 1536
#define NEG_INF -1000000000.0f

// ws layout (float offsets)
#define WS_Q1    0          // 256*512
#define WS_QF    131072     // 256*512
#define WS_WT0   262144     // 512*512
#define WS_WTF   524288     // 512*512
#define WS_PACC  786432     // 256*2*512  (aliased by WS_E after layer combines done)
#define WS_PM    1048576    // 256*2*16   (aliased by WS_SM)
#define WS_PL    1056768    // 256*2*16
#define WS_E     786432     // 256*2*256  raw exp values, final layer
#define WS_SM    1048576    // 256*2*2    (m, sum) per half, final layer

// ---------------------------------------------------------------------------
// Transpose both 512x512 weight matrices so GEMV reads are coalesced.
// ---------------------------------------------------------------------------
__global__ __launch_bounds__(256) void transpose512(
    const float* __restrict__ W0, const float* __restrict__ Wf,
    float* __restrict__ Wt0, float* __restrict__ Wtf)
{
    __shared__ float tile[32][33];
    const float* in = blockIdx.z ? Wf : W0;
    float* out      = blockIdx.z ? Wtf : Wt0;
    const int bx = blockIdx.x * 32, by = blockIdx.y * 32;
    const int tx = threadIdx.x, ty = threadIdx.y;
#pragma unroll
    for (int i = 0; i < 32; i += 8)
        tile[ty + i][tx] = in[(size_t)(by + ty + i) * D + bx + tx];
    __syncthreads();
#pragma unroll
    for (int i = 0; i < 32; i += 8)
        out[(size_t)(bx + ty + i) * D + by + tx] = tile[tx][ty + i];
}

// ---------------------------------------------------------------------------
// Attention partial: grid (2, BSZ), 512 threads (8 waves).
// Block (h, b) streams nodes [h*250, h*250+250) with online softmax per head,
// then combines its 8 wave-states and writes ONE unnormalized partial
// (m[16], l[16], acc[512]) to ws. No GEMV here — epilogue is tiny, and with
// 2 blocks/CU the other block keeps HBM busy during it.
// ---------------------------------------------------------------------------
__global__ __launch_bounds__(512) void attn_partial(
    const float* __restrict__ q_in,
    const float* __restrict__ Katt,
    const float* __restrict__ Vatt,
    const unsigned char* __restrict__ mask,
    float* __restrict__ pacc,
    float* __restrict__ pm,
    float* __restrict__ pl,
    int loff)
{
    __shared__ __align__(16) float part_acc[8 * D];    // 16 KB
    __shared__ float part_m[8 * H];
    __shared__ float part_l[8 * H];

    const int hhalf = blockIdx.x;
    const int b = blockIdx.y;
    const int t = threadIdx.x;
    const int r = t & 63;     // lane: dims [r*8, r*8+8) ; head = r>>2
    const int g = t >> 6;     // wave id (8 rows in flight)

    const float* qp = q_in + (size_t)b * D + r * 8;
    const float4 qa = *reinterpret_cast<const float4*>(qp);
    const float4 qb = *reinterpret_cast<const float4*>(qp + 4);

    const float* Kb = Katt + (size_t)b * NN * KSTRIDE + loff;
    const float* Vb = Vatt + (size_t)b * NN * KSTRIDE + loff;
    const unsigned char* mb = mask + (size_t)b * NN;

    const int n0 = hhalf * NH;
    const int n1 = n0 + NH;

    float m = -3.4e38f, lsum = 0.f;
    float4 acc0 = {0.f, 0.f, 0.f, 0.f};
    float4 acc1 = {0.f, 0.f, 0.f, 0.f};

#pragma unroll 2
    for (int n = n0 + g; n < n1; n += 8) {
        const float* kr = Kb + (size_t)n * KSTRIDE + r * 8;
        const float* vr = Vb + (size_t)n * KSTRIDE + r * 8;
        const float4 ka  = *reinterpret_cast<const float4*>(kr);
        const float4 kb4 = *reinterpret_cast<const float4*>(kr + 4);
        const float4 va  = *reinterpret_cast<const float4*>(vr);
        const float4 vb4 = *reinterpret_cast<const float4*>(vr + 4);

        float s = qa.x * ka.x + qa.y * ka.y + qa.z * ka.z + qa.w * ka.w
                + qb.x * kb4.x + qb.y * kb4.y + qb.z * kb4.z + qb.w * kb4.w;
        s += __shfl_xor(s, 1);             // 4-lane reduce -> one head
        s += __shfl_xor(s, 2);
        float sc = s * 0.17677669529663687f;   // 1/sqrt(32)
        if (mb[n]) sc = NEG_INF;

        const float mn   = fmaxf(m, sc);
        const float corr = __expf(m - mn);
        const float e    = __expf(sc - mn);
        lsum = lsum * corr + e;
        acc0.x = acc0.x * corr + e * va.x;
        acc0.y = acc0.y * corr + e * va.y;
        acc0.z = acc0.z * corr + e * va.z;
        acc0.w = acc0.w * corr + e * va.w;
        acc1.x = acc1.x * corr + e * vb4.x;
        acc1.y = acc1.y * corr + e * vb4.y;
        acc1.z = acc1.z * corr + e * vb4.z;
        acc1.w = acc1.w * corr + e * vb4.w;
        m = mn;
    }

    *reinterpret_cast<float4*>(part_acc + g * D + r * 8)     = acc0;
    *reinterpret_cast<float4*>(part_acc + g * D + r * 8 + 4) = acc1;
    if ((r & 3) == 0) {
        part_m[g * H + (r >> 2)] = m;
        part_l[g * H + (r >> 2)] = lsum;
    }
    __syncthreads();

    // combine the 8 wave-states -> one partial per block
    {
        const int hd = t >> 5;                 // t in [0,512): output dim t
        float ms = -3.4e38f;
#pragma unroll
        for (int g2 = 0; g2 < 8; ++g2)
            ms = fmaxf(ms, part_m[g2 * H + hd]);
        float ls = 0.f, o = 0.f;
#pragma unroll
        for (int g2 = 0; g2 < 8; ++g2) {
            const float w = __expf(part_m[g2 * H + hd] - ms);
            ls += part_l[g2 * H + hd] * w;
            o  += part_acc[g2 * D + t] * w;
        }
        const size_t pb = (size_t)(b * 2 + hhalf);
        pacc[pb * D + t] = o;                  // unnormalized, relative to ms
        if ((t & 31) == 0) {
            pm[pb * H + hd] = ms;
            pl[pb * H + hd] = ls;
        }
    }
}

// ---------------------------------------------------------------------------
// Combine the 2 half-partials -> attention out -> GEMV (one or two).
// grid BSZ, 1024 threads. dbl=0: q_out = out@W1t + b1.
// dbl=1: q_out = ((out@W1t+b1) @ W2t + b2)   (produces q_final directly)
// ---------------------------------------------------------------------------
__global__ __launch_bounds__(1024) void combine_gemv(
    const float* __restrict__ pacc,
    const float* __restrict__ pm,
    const float* __restrict__ pl,
    const float* __restrict__ Wt1, const float* __restrict__ b1,
    const float* __restrict__ Wt2, const float* __restrict__ b2,
    float* __restrict__ q_out, int dbl)
{
    __shared__ __align__(16) float out_lds[D];
    __shared__ __align__(16) float mid_lds[D];
    __shared__ float gemv_part[2 * D];

    const int b = blockIdx.x;
    const int t = threadIdx.x;

    if (t < D) {
        const int hd = t >> 5;
        const size_t p0 = (size_t)(b * 2 + 0);
        const size_t p1 = (size_t)(b * 2 + 1);
        const float m0 = pm[p0 * H + hd], m1 = pm[p1 * H + hd];
        const float M  = fmaxf(m0, m1);
        const float w0 = __expf(m0 - M), w1 = __expf(m1 - M);
        const float l  = pl[p0 * H + hd] * w0 + pl[p1 * H + hd] * w1;
        out_lds[t] = (pacc[p0 * D + t] * w0 + pacc[p1 * D + t] * w1) / l;
    }
    __syncthreads();

    // GEMV 1
    {
        const int j = t & 511;
        const int half = t >> 9;
        const float* Wp = Wt1 + (size_t)half * 256 * D + j;
        const float* a  = out_lds + half * 256;
        float acc = 0.f;
#pragma unroll 4
        for (int k = 0; k < 256; ++k)
            acc += a[k] * Wp[(size_t)k * D];
        gemv_part[half * D + j] = acc;
    }
    __syncthreads();
    if (t < D) mid_lds[t] = gemv_part[t] + gemv_part[D + t] + b1[t];

    if (!dbl) {
        if (t < D) q_out[(size_t)b * D + t] = mid_lds[t];
        return;
    }
    __syncthreads();

    // GEMV 2
    {
        const int j = t & 511;
        const int half = t >> 9;
        const float* Wp = Wt2 + (size_t)half * 256 * D + j;
        const float* a  = mid_lds + half * 256;
        float acc = 0.f;
#pragma unroll 4
        for (int k = 0; k < 256; ++k)
            acc += a[k] * Wp[(size_t)k * D];
        gemv_part[half * D + j] = acc;
    }
    __syncthreads();
    if (t < D)
        q_out[(size_t)b * D + t] = gemv_part[t] + gemv_part[D + t] + b2[t];
}

// ---------------------------------------------------------------------------
// Final partial: grid (2, BSZ), 512 threads. Pure K-streaming (qf is ready).
// Each wave: one node per iter, lane owns 8 dims, 6-shuffle reduce.
// Writes raw exp values (relative to half-local max) + (m, sum) to ws.
// ---------------------------------------------------------------------------
__global__ __launch_bounds__(512) void final_partial(
    const float* __restrict__ qf,
    const float* __restrict__ Katt,
    const unsigned char* __restrict__ mask,
    float* __restrict__ e_ws,
    float* __restrict__ sm_ws)
{
    __shared__ __align__(16) float q_lds[D];
    __shared__ float s_lds[NH];
    __shared__ float red[8];
    __shared__ float bm;

    const int hhalf = blockIdx.x;
    const int b = blockIdx.y;
    const int t = threadIdx.x;
    const int l = t & 63;
    const int wv = t >> 6;

    q_lds[t] = qf[(size_t)b * D + t];
    __syncthreads();

    const float* qp = q_lds + l * 8;
    const float4 q0 = *reinterpret_cast<const float4*>(qp);
    const float4 q1 = *reinterpret_cast<const float4*>(qp + 4);

    const float* Kb = Katt + (size_t)b * NN * KSTRIDE + 1024;
    const unsigned char* mb = mask + (size_t)b * NN;
    const int n0 = hhalf * NH;

#pragma unroll 2
    for (int nl = wv; nl < NH; nl += 8) {
        const int n = n0 + nl;
        const float* kr = Kb + (size_t)n * KSTRIDE + l * 8;
        const float4 k0 = *reinterpret_cast<const float4*>(kr);
        const float4 k1 = *reinterpret_cast<const float4*>(kr + 4);
        float s = q0.x * k0.x + q0.y * k0.y + q0.z * k0.z + q0.w * k0.w
                + q1.x * k1.x + q1.y * k1.y + q1.z * k1.z + q1.w * k1.w;
#pragma unroll
        for (int o = 1; o < 64; o <<= 1) s += __shfl_xor(s, o);
        if (l == 0) {
            float sc = 10.0f * tanhf(s * 0.044194173824159216f);  // 10*tanh(s/sqrt(512))
            if (mb[n]) sc = NEG_INF;
            s_lds[nl] = sc;
        }
    }
    __syncthreads();

    // half-local max
    const float v = (t < NH) ? s_lds[t] : -3.4e38f;
    float m = v;
#pragma unroll
    for (int o = 1; o < 64; o <<= 1) m = fmaxf(m, __shfl_xor(m, o));
    if (l == 0) red[wv] = m;
    __syncthreads();
    if (t == 0) {
        float mm = red[0];
#pragma unroll
        for (int i = 1; i < 8; ++i) mm = fmaxf(mm, red[i]);
        bm = mm;
    }
    __syncthreads();
    const float e = (t < NH) ? __expf(v - bm) : 0.f;
    float ssum = e;
#pragma unroll
    for (int o = 1; o < 64; o <<= 1) ssum += __shfl_xor(ssum, o);
    if (l == 0) red[wv] = ssum;
    __syncthreads();

    const size_t pb = (size_t)(b * 2 + hhalf);
    if (t < NH) e_ws[pb * 256 + t] = e;
    if (t == 0) {
        float s2 = 0.f;
#pragma unroll
        for (int i = 0; i < 8; ++i) s2 += red[i];
        sm_ws[pb * 2]     = bm;
        sm_ws[pb * 2 + 1] = s2;
    }
}

// ---------------------------------------------------------------------------
// Merge the two softmax halves -> final output weights (256 x 500).
// ---------------------------------------------------------------------------
__global__ __launch_bounds__(512) void final_merge(
    const float* __restrict__ e_ws,
    const float* __restrict__ sm_ws,
    float* __restrict__ out)
{
    const int b = blockIdx.x;
    const int t = threadIdx.x;

    const float m0 = sm_ws[(size_t)(b * 2) * 2];
    const float s0 = sm_ws[(size_t)(b * 2) * 2 + 1];
    const float m1 = sm_ws[(size_t)(b * 2 + 1) * 2];
    const float s1 = sm_ws[(size_t)(b * 2 + 1) * 2 + 1];
    const float M  = fmaxf(m0, m1);
    const float w0 = __expf(m0 - M), w1 = __expf(m1 - M);
    const float inv = 1.0f / (s0 * w0 + s1 * w1);

    if (t < NN) {
        const int h = (t >= NH) ? 1 : 0;
        const int idx = t - h * NH;
        const float e = e_ws[(size_t)(b * 2 + h) * 256 + idx];
        out[(size_t)b * NN + t] = e * (h ? w1 : w0) * inv;
    }
}

// ---------------------------------------------------------------------------
extern "C" void kernel_launch(void* const* d_in, const int* in_sizes, int n_in,
                              void* d_out, int out_size, void* d_ws, size_t ws_size,
                              hipStream_t stream) {
    const float* query = (const float*)d_in[0];
    const float* Katt  = (const float*)d_in[1];
    const float* Vatt  = (const float*)d_in[2];
    const unsigned char* mask = (const unsigned char*)d_in[3];
    const float* W0w = (const float*)d_in[4];
    const float* W0b = (const float*)d_in[5];
    const float* Wfw = (const float*)d_in[6];
    const float* Wfb = (const float*)d_in[7];

    float* out = (float*)d_out;
    float* ws  = (float*)d_ws;
    float* q1   = ws + WS_Q1;
    float* qf   = ws + WS_QF;
    float* Wt0  = ws + WS_WT0;
    float* Wtf  = ws + WS_WTF;
    float* pacc = ws + WS_PACC;
    float* pm   = ws + WS_PM;
    float* pl   = ws + WS_PL;
    float* e_ws = ws + WS_E;     // aliases pacc (dead by then)
    float* sm   = ws + WS_SM;    // aliases pm

    transpose512<<<dim3(16, 16, 2), dim3(32, 8), 0, stream>>>(W0w, Wfw, Wt0, Wtf);

    attn_partial<<<dim3(2, BSZ), 512, 0, stream>>>(query, Katt, Vatt, mask,
                                                   pacc, pm, pl, 0);
    combine_gemv<<<BSZ, 1024, 0, stream>>>(pacc, pm, pl, Wt0, W0b,
                                           nullptr, nullptr, q1, 0);

    attn_partial<<<dim3(2, BSZ), 512, 0, stream>>>(q1, Katt, Vatt, mask,
                                                   pacc, pm, pl, 512);
    combine_gemv<<<BSZ, 1024, 0, stream>>>(pacc, pm, pl, Wt0, W0b,
                                           Wtf, Wfb, qf, 1);

    final_partial<<<dim3(2, BSZ), 512, 0, stream>>>(qf, Katt, mask, e_ws, sm);
    final_merge<<<BSZ, 512, 0, stream>>>(e_ws, sm, out);
}

// Round 4
// 310.588 us; speedup vs baseline: 1.1236x; 1.1236x over previous
//
#include <hip/hip_runtime.h>
#include <cstdint>
#include <cstddef>

#define BSZ 256
#define NN 500
#define D 512
#define H 16
#define KSTRIDE 1536
#define NEG_INF -1000000000.0f

// ws layout (float offsets)
#define WS_Q1    0          // 256*512
#define WS_QF    131072     // 256*512
#define WS_WT0   262144     // 512*512  W0^T
#define WS_WCT   524288     // 512*512  (Wqf @ W0)^T
#define WS_BC    786432     // 512      combined bias

// ---------------------------------------------------------------------------
// Prep: z=0 -> Wt0 = W0^T (for layer-0 GEMV).
//       z=1 -> Wct = (Wqf @ W0)^T tile GEMM + bc = Wqf@b0 + bqf.
// grid (16,16,2), 256 threads.
// ---------------------------------------------------------------------------
__global__ __launch_bounds__(256) void prep(
    const float* __restrict__ W0, const float* __restrict__ Wqf,
    const float* __restrict__ b0, const float* __restrict__ bqf,
    float* __restrict__ Wt0, float* __restrict__ Wct, float* __restrict__ bc)
{
    __shared__ float As[32][33];
    __shared__ float Bs[32][33];

    const int t  = threadIdx.x;
    const int bx = blockIdx.x, by = blockIdx.y;

    if (blockIdx.z == 0) {
        // transpose W0 -> Wt0  (Wt0[d][j] = W0[j][d])
        const int tx = t & 31, ty = t >> 5;
        const int c0 = bx * 32, r0 = by * 32;
#pragma unroll
        for (int i = 0; i < 32; i += 8)
            As[ty + i][tx] = W0[(size_t)(r0 + ty + i) * D + c0 + tx];
        __syncthreads();
#pragma unroll
        for (int i = 0; i < 32; i += 8)
            Wt0[(size_t)(c0 + ty + i) * D + r0 + tx] = As[tx][ty + i];
        return;
    }

    // ---- z == 1 : Wc tile GEMM.  Wc[j,d] = sum_k Wqf[j,k] * W0[k,d] --------
    const int j0 = by * 32;          // output row tile (j)
    const int d0 = bx * 32;          // output col tile (d)
    const int lr  = t >> 3;          // 0..31  (stage row)
    const int lc4 = (t & 7) * 4;     // 0,4,..,28
    const int ty2 = (t >> 4) * 2;    // 2x2 micro-tile
    const int tx2 = (t & 15) * 2;

    float c00 = 0.f, c01 = 0.f, c10 = 0.f, c11 = 0.f;

    for (int k0 = 0; k0 < D; k0 += 32) {
        const float4 av = *reinterpret_cast<const float4*>(
            Wqf + (size_t)(j0 + lr) * D + k0 + lc4);
        const float4 bv = *reinterpret_cast<const float4*>(
            W0 + (size_t)(k0 + lr) * D + d0 + lc4);
        As[lr][lc4] = av.x; As[lr][lc4 + 1] = av.y;
        As[lr][lc4 + 2] = av.z; As[lr][lc4 + 3] = av.w;
        Bs[lr][lc4] = bv.x; Bs[lr][lc4 + 1] = bv.y;
        Bs[lr][lc4 + 2] = bv.z; Bs[lr][lc4 + 3] = bv.w;
        __syncthreads();
#pragma unroll 8
        for (int kk = 0; kk < 32; ++kk) {
            const float a0 = As[ty2][kk], a1 = As[ty2 + 1][kk];
            const float v0 = Bs[kk][tx2], v1 = Bs[kk][tx2 + 1];
            c00 += a0 * v0; c01 += a0 * v1;
            c10 += a1 * v0; c11 += a1 * v1;
        }
        __syncthreads();
    }

    // stage transposed (T[d_local][j_local]) and store coalesced
    As[tx2][ty2]         = c00;
    As[tx2 + 1][ty2]     = c01;
    As[tx2][ty2 + 1]     = c10;
    As[tx2 + 1][ty2 + 1] = c11;
    __syncthreads();
#pragma unroll
    for (int i = 0; i < 4; ++i)
        Wct[(size_t)(d0 + lr) * D + j0 + lc4 + i] = As[lr][lc4 + i];

    // bc = Wqf @ b0 + bqf   (only one block column needs to do it)
    if (bx == 0 && t < 32) {
        const int j = j0 + t;
        float s = 0.f;
        for (int k = 0; k < D; ++k)
            s += Wqf[(size_t)j * D + k] * b0[k];
        bc[j] = s + bqf[j];
    }
}

// ---------------------------------------------------------------------------
// Fused online-softmax attention layer + output GEMV (round-2 validated).
// One block (1024 threads = 16 waves) per batch element.
// ---------------------------------------------------------------------------
__global__ __launch_bounds__(1024) void attn_layer_fused(
    const float* __restrict__ q_in,
    const float* __restrict__ Katt,
    const float* __restrict__ Vatt,
    const unsigned char* __restrict__ mask,
    const float* __restrict__ Wt,     // Wt[d][j] layout
    const float* __restrict__ bias,
    float* __restrict__ q_out,
    int loff)
{
    __shared__ __align__(16) float part_acc[16 * D];   // 32 KB
    __shared__ float part_m[16 * H];
    __shared__ float part_l[16 * H];
    __shared__ __align__(16) float out_lds[D];
    __shared__ float gemv_part[2 * D];

    const int b = blockIdx.x;
    const int t = threadIdx.x;
    const int r = t & 63;     // lane: dims [r*8, r*8+8) ; head = r>>2
    const int g = t >> 6;     // wave id (16 rows in flight)

    const float* qp = q_in + (size_t)b * D + r * 8;
    const float4 qa = *reinterpret_cast<const float4*>(qp);
    const float4 qb = *reinterpret_cast<const float4*>(qp + 4);

    const float* Kb = Katt + (size_t)b * NN * KSTRIDE + loff;
    const float* Vb = Vatt + (size_t)b * NN * KSTRIDE + loff;
    const unsigned char* mb = mask + (size_t)b * NN;

    float m = -3.4e38f, lsum = 0.f;
    float4 acc0 = {0.f, 0.f, 0.f, 0.f};
    float4 acc1 = {0.f, 0.f, 0.f, 0.f};

#pragma unroll 2
    for (int n = g; n < NN; n += 16) {
        const float* kr = Kb + (size_t)n * KSTRIDE + r * 8;
        const float* vr = Vb + (size_t)n * KSTRIDE + r * 8;
        const float4 ka  = *reinterpret_cast<const float4*>(kr);
        const float4 kb4 = *reinterpret_cast<const float4*>(kr + 4);
        const float4 va  = *reinterpret_cast<const float4*>(vr);
        const float4 vb4 = *reinterpret_cast<const float4*>(vr + 4);

        float s = qa.x * ka.x + qa.y * ka.y + qa.z * ka.z + qa.w * ka.w
                + qb.x * kb4.x + qb.y * kb4.y + qb.z * kb4.z + qb.w * kb4.w;
        s += __shfl_xor(s, 1);             // 4-lane reduce -> one head
        s += __shfl_xor(s, 2);
        float sc = s * 0.17677669529663687f;   // 1/sqrt(32)
        if (mb[n]) sc = NEG_INF;

        const float mn   = fmaxf(m, sc);
        const float corr = __expf(m - mn);
        const float e    = __expf(sc - mn);
        lsum = lsum * corr + e;
        acc0.x = acc0.x * corr + e * va.x;
        acc0.y = acc0.y * corr + e * va.y;
        acc0.z = acc0.z * corr + e * va.z;
        acc0.w = acc0.w * corr + e * va.w;
        acc1.x = acc1.x * corr + e * vb4.x;
        acc1.y = acc1.y * corr + e * vb4.y;
        acc1.z = acc1.z * corr + e * vb4.z;
        acc1.w = acc1.w * corr + e * vb4.w;
        m = mn;
    }

    *reinterpret_cast<float4*>(part_acc + g * D + r * 8)     = acc0;
    *reinterpret_cast<float4*>(part_acc + g * D + r * 8 + 4) = acc1;
    if ((r & 3) == 0) {
        part_m[g * H + (r >> 2)] = m;
        part_l[g * H + (r >> 2)] = lsum;
    }
    __syncthreads();

    // combine the 16 wave-states
    if (t < D) {
        const int hd = t >> 5;
        float ms = -3.4e38f;
#pragma unroll
        for (int g2 = 0; g2 < 16; ++g2)
            ms = fmaxf(ms, part_m[g2 * H + hd]);
        float ls = 0.f, o = 0.f;
#pragma unroll
        for (int g2 = 0; g2 < 16; ++g2) {
            const float w = __expf(part_m[g2 * H + hd] - ms);
            ls += part_l[g2 * H + hd] * w;
            o  += part_acc[g2 * D + t] * w;
        }
        out_lds[t] = o / ls;
    }
    __syncthreads();

    // GEMV q_out = out @ W^T + bias   (Wt[d][j], coalesced in j)
    {
        const int j = t & 511;
        const int half = t >> 9;
        const float* Wp = Wt + (size_t)half * 256 * D + j;
        const float* a  = out_lds + half * 256;
        float acc = 0.f;
#pragma unroll 4
        for (int k = 0; k < 256; ++k)
            acc += a[k] * Wp[(size_t)k * D];
        gemv_part[half * D + j] = acc;
    }
    __syncthreads();
    if (t < D)
        q_out[(size_t)b * D + t] = gemv_part[t] + gemv_part[D + t] + bias[t];
}

// ---------------------------------------------------------------------------
// Final layer: PURE K-streaming (q_final precomputed by layer-1 epilogue).
// scores -> 10*tanh(s/sqrt(512)) -> mask -> softmax -> out (256 x 500).
// 32 lanes per node, 32 nodes in flight per block.
// ---------------------------------------------------------------------------
__global__ __launch_bounds__(1024) void final_layer(
    const float* __restrict__ qf,
    const float* __restrict__ Katt,
    const unsigned char* __restrict__ mask,
    float* __restrict__ out)
{
    __shared__ __align__(16) float qf_lds[D];
    __shared__ float s_lds[NN];
    __shared__ float red[16];
    __shared__ float bm, bs;

    const int b = blockIdx.x;
    const int t = threadIdx.x;

    if (t < D) qf_lds[t] = qf[(size_t)b * D + t];
    __syncthreads();

    const int wv   = t >> 6;
    const int l    = t & 63;
    const int half = l >> 5;
    const int l32  = l & 31;

    const float* qpp = qf_lds + l32 * 16;
    const float4 q0 = *reinterpret_cast<const float4*>(qpp);
    const float4 q1 = *reinterpret_cast<const float4*>(qpp + 4);
    const float4 q2 = *reinterpret_cast<const float4*>(qpp + 8);
    const float4 q3 = *reinterpret_cast<const float4*>(qpp + 12);

    const float* Kb = Katt + (size_t)b * NN * KSTRIDE + 1024;
    const unsigned char* mb = mask + (size_t)b * NN;

    for (int n = wv * 2 + half; n < NN; n += 32) {
        const float* kr = Kb + (size_t)n * KSTRIDE + l32 * 16;
        const float4 k0 = *reinterpret_cast<const float4*>(kr);
        const float4 k1 = *reinterpret_cast<const float4*>(kr + 4);
        const float4 k2 = *reinterpret_cast<const float4*>(kr + 8);
        const float4 k3 = *reinterpret_cast<const float4*>(kr + 12);
        float s = q0.x * k0.x + q0.y * k0.y + q0.z * k0.z + q0.w * k0.w
                + q1.x * k1.x + q1.y * k1.y + q1.z * k1.z + q1.w * k1.w
                + q2.x * k2.x + q2.y * k2.y + q2.z * k2.z + q2.w * k2.w
                + q3.x * k3.x + q3.y * k3.y + q3.z * k3.z + q3.w * k3.w;
#pragma unroll
        for (int o = 1; o < 32; o <<= 1) s += __shfl_xor(s, o);
        if (l32 == 0) {
            float sc = 10.0f * tanhf(s * 0.044194173824159216f);  // 10*tanh(s/sqrt(512))
            if (mb[n]) sc = NEG_INF;
            s_lds[n] = sc;
        }
    }
    __syncthreads();

    // block softmax over 500
    const float v = (t < NN) ? s_lds[t] : -3.4e38f;
    float m = v;
#pragma unroll
    for (int o = 1; o < 64; o <<= 1) m = fmaxf(m, __shfl_xor(m, o));
    if (l == 0) red[wv] = m;
    __syncthreads();
    if (t == 0) {
        float mm = red[0];
#pragma unroll
        for (int i = 1; i < 16; ++i) mm = fmaxf(mm, red[i]);
        bm = mm;
    }
    __syncthreads();
    const float e = (t < NN) ? __expf(v - bm) : 0.f;
    float ssum = e;
#pragma unroll
    for (int o = 1; o < 64; o <<= 1) ssum += __shfl_xor(ssum, o);
    if (l == 0) red[wv] = ssum;
    __syncthreads();
    if (t == 0) {
        float s2 = 0.f;
#pragma unroll
        for (int i = 0; i < 16; ++i) s2 += red[i];
        bs = 1.0f / s2;
    }
    __syncthreads();
    if (t < NN) out[(size_t)b * NN + t] = e * bs;
}

// ---------------------------------------------------------------------------
extern "C" void kernel_launch(void* const* d_in, const int* in_sizes, int n_in,
                              void* d_out, int out_size, void* d_ws, size_t ws_size,
                              hipStream_t stream) {
    const float* query = (const float*)d_in[0];
    const float* Katt  = (const float*)d_in[1];
    const float* Vatt  = (const float*)d_in[2];
    const unsigned char* mask = (const unsigned char*)d_in[3];
    const float* W0w = (const float*)d_in[4];
    const float* W0b = (const float*)d_in[5];
    const float* Wfw = (const float*)d_in[6];
    const float* Wfb = (const float*)d_in[7];

    float* out = (float*)d_out;
    float* ws  = (float*)d_ws;
    float* q1  = ws + WS_Q1;
    float* qf  = ws + WS_QF;
    float* Wt0 = ws + WS_WT0;
    float* Wct = ws + WS_WCT;
    float* bc  = ws + WS_BC;

    prep<<<dim3(16, 16, 2), 256, 0, stream>>>(W0w, Wfw, W0b, Wfb, Wt0, Wct, bc);

    attn_layer_fused<<<BSZ, 1024, 0, stream>>>(query, Katt, Vatt, mask,
                                               Wt0, W0b, q1, 0);
    attn_layer_fused<<<BSZ, 1024, 0, stream>>>(q1, Katt, Vatt, mask,
                                               Wct, bc, qf, 512);
    final_layer<<<BSZ, 1024, 0, stream>>>(qf, Katt, mask, out);
}

// Round 5
// 309.029 us; speedup vs baseline: 1.1293x; 1.0050x over previous
//
#include <hip/hip_runtime.h>
#include <cstdint>
#include <cstddef>

#define BSZ 256
#define NN 500
#define D 512
#define H 16
#define KSTRIDE 1536
#define NEG_INF -1000000000.0f

// ws layout (float offsets)
#define WS_WT0   0          // 512*512  W0^T
#define WS_WCT   262144     // 512*512  (Wqf @ W0)^T
#define WS_BC    524288     // 512      combined bias

// ---------------------------------------------------------------------------
// Prep: z=0 -> Wt0 = W0^T.  z=1 -> Wct = (Wqf @ W0)^T + bc = Wqf@b0 + bqf.
// (validated round 4)
// ---------------------------------------------------------------------------
__global__ __launch_bounds__(256) void prep(
    const float* __restrict__ W0, const float* __restrict__ Wqf,
    const float* __restrict__ b0, const float* __restrict__ bqf,
    float* __restrict__ Wt0, float* __restrict__ Wct, float* __restrict__ bc)
{
    __shared__ float As[32][33];
    __shared__ float Bs[32][33];

    const int t  = threadIdx.x;
    const int bx = blockIdx.x, by = blockIdx.y;

    if (blockIdx.z == 0) {
        const int tx = t & 31, ty = t >> 5;
        const int c0 = bx * 32, r0 = by * 32;
#pragma unroll
        for (int i = 0; i < 32; i += 8)
            As[ty + i][tx] = W0[(size_t)(r0 + ty + i) * D + c0 + tx];
        __syncthreads();
#pragma unroll
        for (int i = 0; i < 32; i += 8)
            Wt0[(size_t)(c0 + ty + i) * D + r0 + tx] = As[tx][ty + i];
        return;
    }

    // Wc[j,d] = sum_k Wqf[j,k] * W0[k,d] ; store transposed Wct[d][j]
    const int j0 = by * 32;
    const int d0 = bx * 32;
    const int lr  = t >> 3;
    const int lc4 = (t & 7) * 4;
    const int ty2 = (t >> 4) * 2;
    const int tx2 = (t & 15) * 2;

    float c00 = 0.f, c01 = 0.f, c10 = 0.f, c11 = 0.f;

    for (int k0 = 0; k0 < D; k0 += 32) {
        const float4 av = *reinterpret_cast<const float4*>(
            Wqf + (size_t)(j0 + lr) * D + k0 + lc4);
        const float4 bv = *reinterpret_cast<const float4*>(
            W0 + (size_t)(k0 + lr) * D + d0 + lc4);
        As[lr][lc4] = av.x; As[lr][lc4 + 1] = av.y;
        As[lr][lc4 + 2] = av.z; As[lr][lc4 + 3] = av.w;
        Bs[lr][lc4] = bv.x; Bs[lr][lc4 + 1] = bv.y;
        Bs[lr][lc4 + 2] = bv.z; Bs[lr][lc4 + 3] = bv.w;
        __syncthreads();
#pragma unroll 8
        for (int kk = 0; kk < 32; ++kk) {
            const float a0 = As[ty2][kk], a1 = As[ty2 + 1][kk];
            const float v0 = Bs[kk][tx2], v1 = Bs[kk][tx2 + 1];
            c00 += a0 * v0; c01 += a0 * v1;
            c10 += a1 * v0; c11 += a1 * v1;
        }
        __syncthreads();
    }

    As[tx2][ty2]         = c00;
    As[tx2 + 1][ty2]     = c01;
    As[tx2][ty2 + 1]     = c10;
    As[tx2 + 1][ty2 + 1] = c11;
    __syncthreads();
#pragma unroll
    for (int i = 0; i < 4; ++i)
        Wct[(size_t)(d0 + lr) * D + j0 + lc4 + i] = As[lr][lc4 + i];

    if (bx == 0 && t < 32) {
        const int j = j0 + t;
        float s = 0.f;
        for (int k = 0; k < D; ++k)
            s += Wqf[(size_t)j * D + k] * b0[k];
        bc[j] = s + bqf[j];
    }
}

// ---------------------------------------------------------------------------
// helpers
// ---------------------------------------------------------------------------
__device__ __forceinline__ float4 ld4(const float* p) {
    return *reinterpret_cast<const float4*>(p);
}

__device__ __forceinline__ float head_score(const float4 qa, const float4 qb,
                                            const float4 k0, const float4 k1)
{
    float s = qa.x * k0.x + qa.y * k0.y + qa.z * k0.z + qa.w * k0.w
            + qb.x * k1.x + qb.y * k1.y + qb.z * k1.z + qb.w * k1.w;
    s += __shfl_xor(s, 1);       // 4-lane reduce -> one head (32 dims)
    s += __shfl_xor(s, 2);
    return s * 0.17677669529663687f;   // 1/sqrt(32)
}

__device__ __forceinline__ void online_upd(float& m, float& l, float4& a0, float4& a1,
                                           const float sc, const float4 v0, const float4 v1)
{
    const float mn   = fmaxf(m, sc);
    const float corr = __expf(m - mn);
    const float e    = __expf(sc - mn);
    l = l * corr + e;
    a0.x = a0.x * corr + e * v0.x;
    a0.y = a0.y * corr + e * v0.y;
    a0.z = a0.z * corr + e * v0.z;
    a0.w = a0.w * corr + e * v0.w;
    a1.x = a1.x * corr + e * v1.x;
    a1.y = a1.y * corr + e * v1.y;
    a1.z = a1.z * corr + e * v1.z;
    a1.w = a1.w * corr + e * v1.w;
    m = mn;
}

// Stream one attention layer with TWO independent online chains per wave
// (nodes n and n+16 each iter), then merge and deposit per-wave partials.
__device__ __forceinline__ void stream_attn(
    const float4 qa, const float4 qb,
    const float* __restrict__ Kb, const float* __restrict__ Vb,
    const unsigned char* __restrict__ mask_lds,
    const int g, const int r,
    float* __restrict__ part_acc, float* __restrict__ part_m,
    float* __restrict__ part_l)
{
    float mA = -3.4e38f, lA = 0.f;
    float4 aA0 = {0.f,0.f,0.f,0.f}, aA1 = {0.f,0.f,0.f,0.f};
    float mB = -3.4e38f, lB = 0.f;
    float4 aB0 = {0.f,0.f,0.f,0.f}, aB1 = {0.f,0.f,0.f,0.f};

    for (int n = g; n < NN; n += 32) {
        const int n2 = n + 16;
        const float* krA = Kb + (size_t)n * KSTRIDE + r * 8;
        const float* vrA = Vb + (size_t)n * KSTRIDE + r * 8;
        const float4 kA0 = ld4(krA), kA1 = ld4(krA + 4);
        const float4 vA0 = ld4(vrA), vA1 = ld4(vrA + 4);

        if (n2 < NN) {                       // wave-uniform branch
            const float* krB = Kb + (size_t)n2 * KSTRIDE + r * 8;
            const float* vrB = Vb + (size_t)n2 * KSTRIDE + r * 8;
            const float4 kB0 = ld4(krB), kB1 = ld4(krB + 4);
            const float4 vB0 = ld4(vrB), vB1 = ld4(vrB + 4);

            float scA = head_score(qa, qb, kA0, kA1);
            if (mask_lds[n]) scA = NEG_INF;
            online_upd(mA, lA, aA0, aA1, scA, vA0, vA1);

            float scB = head_score(qa, qb, kB0, kB1);
            if (mask_lds[n2]) scB = NEG_INF;
            online_upd(mB, lB, aB0, aB1, scB, vB0, vB1);
        } else {
            float scA = head_score(qa, qb, kA0, kA1);
            if (mask_lds[n]) scA = NEG_INF;
            online_upd(mA, lA, aA0, aA1, scA, vA0, vA1);
        }
    }

    // merge chain B into chain A (exact)
    const float mn = fmaxf(mA, mB);
    const float wA = __expf(mA - mn), wB = __expf(mB - mn);
    const float lm = lA * wA + lB * wB;
    float4 o0, o1;
    o0.x = aA0.x * wA + aB0.x * wB;  o0.y = aA0.y * wA + aB0.y * wB;
    o0.z = aA0.z * wA + aB0.z * wB;  o0.w = aA0.w * wA + aB0.w * wB;
    o1.x = aA1.x * wA + aB1.x * wB;  o1.y = aA1.y * wA + aB1.y * wB;
    o1.z = aA1.z * wA + aB1.z * wB;  o1.w = aA1.w * wA + aB1.w * wB;

    *reinterpret_cast<float4*>(part_acc + g * D + r * 8)     = o0;
    *reinterpret_cast<float4*>(part_acc + g * D + r * 8 + 4) = o1;
    if ((r & 3) == 0) {
        part_m[g * H + (r >> 2)] = mn;
        part_l[g * H + (r >> 2)] = lm;
    }
}

// ---------------------------------------------------------------------------
// Monolith: one block (1024 threads) carries batch b through all 3 layers.
// No global round-trips for q; mask slice preloaded to LDS.
// ---------------------------------------------------------------------------
__global__ __launch_bounds__(1024) void fused_all(
    const float* __restrict__ query,
    const float* __restrict__ Katt,
    const float* __restrict__ Vatt,
    const unsigned char* __restrict__ mask,
    const float* __restrict__ Wt0, const float* __restrict__ b0,
    const float* __restrict__ Wct, const float* __restrict__ bc,
    float* __restrict__ out)
{
    __shared__ __align__(16) float part_acc[16 * D];   // 32 KB
    __shared__ float part_m[16 * H];
    __shared__ float part_l[16 * H];
    __shared__ __align__(16) float out_lds[D];
    __shared__ __align__(16) float q_lds[D];
    __shared__ float gemv_part[2 * D];
    __shared__ unsigned char mask_lds[512];
    __shared__ float s_lds[NN];
    __shared__ float red[16];
    __shared__ float bm, bs;

    const int b = blockIdx.x;
    const int t = threadIdx.x;
    const int r = t & 63;     // lane: dims [r*8, r*8+8) ; head = r>>2
    const int g = t >> 6;     // wave id (16 node-groups in flight)

    if (t < 512) mask_lds[t] = (t < NN) ? mask[(size_t)b * NN + t] : 0;

    const float* Kbase = Katt + (size_t)b * NN * KSTRIDE;
    const float* Vbase = Vatt + (size_t)b * NN * KSTRIDE;

    float4 qa = ld4(query + (size_t)b * D + r * 8);
    float4 qb = ld4(query + (size_t)b * D + r * 8 + 4);
    __syncthreads();

    // ======================= layers 0 and 1 =======================
#pragma unroll 1
    for (int layer = 0; layer < 2; ++layer) {
        const int loff = layer * 512;
        stream_attn(qa, qb, Kbase + loff, Vbase + loff, mask_lds, g, r,
                    part_acc, part_m, part_l);
        __syncthreads();

        // combine 16 wave-states -> normalized attention output
        if (t < D) {
            const int hd = t >> 5;
            float ms = -3.4e38f;
#pragma unroll
            for (int g2 = 0; g2 < 16; ++g2)
                ms = fmaxf(ms, part_m[g2 * H + hd]);
            float ls = 0.f, o = 0.f;
#pragma unroll
            for (int g2 = 0; g2 < 16; ++g2) {
                const float w = __expf(part_m[g2 * H + hd] - ms);
                ls += part_l[g2 * H + hd] * w;
                o  += part_acc[g2 * D + t] * w;
            }
            out_lds[t] = o / ls;
        }
        __syncthreads();

        // GEMV: q = out @ W^T + bias   (layer0: Wt0/b0 -> q1; layer1: Wct/bc -> qf)
        {
            const float* Wt   = layer ? Wct : Wt0;
            const float* bias = layer ? bc  : b0;
            const int j = t & 511;
            const int half = t >> 9;
            const float* Wp = Wt + (size_t)half * 256 * D + j;
            const float* a  = out_lds + half * 256;
            float acc = 0.f;
#pragma unroll 4
            for (int k = 0; k < 256; ++k)
                acc += a[k] * Wp[(size_t)k * D];
            gemv_part[half * D + j] = acc;
            __syncthreads();
            if (t < D) q_lds[t] = gemv_part[t] + gemv_part[D + t] + bias[t];
            __syncthreads();
        }

        qa = ld4(q_lds + r * 8);
        qb = ld4(q_lds + r * 8 + 4);
    }

    // ======================= final layer =======================
    {
        const int wv   = t >> 6;
        const int l    = t & 63;
        const int half = l >> 5;
        const int l32  = l & 31;

        const float* qpp = q_lds + l32 * 16;
        const float4 f0 = ld4(qpp);
        const float4 f1 = ld4(qpp + 4);
        const float4 f2 = ld4(qpp + 8);
        const float4 f3 = ld4(qpp + 12);

        const float* Kb2 = Kbase + 1024;

        for (int n = wv * 2 + half; n < NN; n += 32) {
            const float* kr = Kb2 + (size_t)n * KSTRIDE + l32 * 16;
            const float4 k0 = ld4(kr);
            const float4 k1 = ld4(kr + 4);
            const float4 k2 = ld4(kr + 8);
            const float4 k3 = ld4(kr + 12);
            float s = f0.x * k0.x + f0.y * k0.y + f0.z * k0.z + f0.w * k0.w
                    + f1.x * k1.x + f1.y * k1.y + f1.z * k1.z + f1.w * k1.w
                    + f2.x * k2.x + f2.y * k2.y + f2.z * k2.z + f2.w * k2.w
                    + f3.x * k3.x + f3.y * k3.y + f3.z * k3.z + f3.w * k3.w;
#pragma unroll
            for (int o = 1; o < 32; o <<= 1) s += __shfl_xor(s, o);
            if (l32 == 0) {
                float sc = 10.0f * tanhf(s * 0.044194173824159216f);  // 10*tanh(s/sqrt(512))
                if (mask_lds[n]) sc = NEG_INF;
                s_lds[n] = sc;
            }
        }
        __syncthreads();

        // block softmax over 500
        const float v = (t < NN) ? s_lds[t] : -3.4e38f;
        float m = v;
#pragma unroll
        for (int o = 1; o < 64; o <<= 1) m = fmaxf(m, __shfl_xor(m, o));
        if (l == 0) red[wv] = m;
        __syncthreads();
        if (t == 0) {
            float mm = red[0];
#pragma unroll
            for (int i = 1; i < 16; ++i) mm = fmaxf(mm, red[i]);
            bm = mm;
        }
        __syncthreads();
        const float e = (t < NN) ? __expf(v - bm) : 0.f;
        float ssum = e;
#pragma unroll
        for (int o = 1; o < 64; o <<= 1) ssum += __shfl_xor(ssum, o);
        if (l == 0) red[wv] = ssum;
        __syncthreads();
        if (t == 0) {
            float s2 = 0.f;
#pragma unroll
            for (int i = 0; i < 16; ++i) s2 += red[i];
            bs = 1.0f / s2;
        }
        __syncthreads();
        if (t < NN) out[(size_t)b * NN + t] = e * bs;
    }
}

// ---------------------------------------------------------------------------
extern "C" void kernel_launch(void* const* d_in, const int* in_sizes, int n_in,
                              void* d_out, int out_size, void* d_ws, size_t ws_size,
                              hipStream_t stream) {
    const float* query = (const float*)d_in[0];
    const float* Katt  = (const float*)d_in[1];
    const float* Vatt  = (const float*)d_in[2];
    const unsigned char* mask = (const unsigned char*)d_in[3];
    const float* W0w = (const float*)d_in[4];
    const float* W0b = (const float*)d_in[5];
    const float* Wfw = (const float*)d_in[6];
    const float* Wfb = (const float*)d_in[7];

    float* out = (float*)d_out;
    float* ws  = (float*)d_ws;
    float* Wt0 = ws + WS_WT0;
    float* Wct = ws + WS_WCT;
    float* bc  = ws + WS_BC;

    prep<<<dim3(16, 16, 2), 256, 0, stream>>>(W0w, Wfw, W0b, Wfb, Wt0, Wct, bc);
    fused_all<<<BSZ, 1024, 0, stream>>>(query, Katt, Vatt, mask,
                                        Wt0, W0b, Wct, bc, out);
}

// Round 7
// 294.303 us; speedup vs baseline: 1.1858x; 1.0500x over previous
//
#include <hip/hip_runtime.h>
#include <cstdint>
#include <cstddef>

#define BSZ 256
#define NN 500
#define D 512
#define H 16
#define KSTRIDE 1536
#define NEG_INF -1000000000.0f

// ws layout (float offsets)
#define WS_WT0   0          // 512*512  W0^T
#define WS_WTF   262144     // 512*512  Wqf^T

typedef float f32x4 __attribute__((ext_vector_type(4)));

// ---------------------------------------------------------------------------
// Prep: transpose W0 and Wqf (z selects) so GEMV reads are coalesced.
// ---------------------------------------------------------------------------
__global__ __launch_bounds__(256) void prep_transpose(
    const float* __restrict__ W0, const float* __restrict__ Wqf,
    float* __restrict__ Wt0, float* __restrict__ Wtf)
{
    __shared__ float tile[32][33];
    const float* in = blockIdx.z ? Wqf : W0;
    float* out      = blockIdx.z ? Wtf : Wt0;
    const int bx = blockIdx.x * 32, by = blockIdx.y * 32;
    const int tx = threadIdx.x & 31, ty = threadIdx.x >> 5;
#pragma unroll
    for (int i = 0; i < 32; i += 8)
        tile[ty + i][tx] = in[(size_t)(by + ty + i) * D + bx + tx];
    __syncthreads();
#pragma unroll
    for (int i = 0; i < 32; i += 8)
        out[(size_t)(bx + ty + i) * D + by + tx] = tile[tx][ty + i];
}

// ---------------------------------------------------------------------------
// helpers
// ---------------------------------------------------------------------------
__device__ __forceinline__ float4 ld4(const float* p) {
    return *reinterpret_cast<const float4*>(p);
}
__device__ __forceinline__ float4 ld4nt(const float* p) {
    f32x4 v = __builtin_nontemporal_load(reinterpret_cast<const f32x4*>(p));
    return float4{v.x, v.y, v.z, v.w};
}

// score for one head (32 dims across 4 lanes), scaled by 1/sqrt(32)
__device__ __forceinline__ float head_score(const float4 qa, const float4 qb,
                                            const float4 k0, const float4 k1)
{
    float s = qa.x * k0.x + qa.y * k0.y + qa.z * k0.z + qa.w * k0.w
            + qb.x * k1.x + qb.y * k1.y + qb.z * k1.z + qb.w * k1.w;
    s += __shfl_xor(s, 1);
    s += __shfl_xor(s, 2);
    return s * 0.17677669529663687f;   // 1/sqrt(32)
}

// no-max online update: e = exp(sc); l += e; acc += e*v   (masked -> e = 0)
__device__ __forceinline__ void upd(float& l, float4& a0, float4& a1,
                                    const float sc, const float4 v0, const float4 v1)
{
    const float e = __expf(sc);
    l += e;
    a0.x += e * v0.x; a0.y += e * v0.y; a0.z += e * v0.z; a0.w += e * v0.w;
    a1.x += e * v1.x; a1.y += e * v1.y; a1.z += e * v1.z; a1.w += e * v1.w;
}

// process one node for one chain
__device__ __forceinline__ void do_node(
    const float4 qa, const float4 qb,
    const float* __restrict__ Kb, const float* __restrict__ Vb,
    const unsigned char* __restrict__ mask_lds,
    const int n, const int r,
    float& l, float4& a0, float4& a1)
{
    const float* kr = Kb + (size_t)n * KSTRIDE + r * 8;
    const float* vr = Vb + (size_t)n * KSTRIDE + r * 8;
    const float4 k0 = ld4nt(kr), k1 = ld4nt(kr + 4);
    const float4 v0 = ld4nt(vr), v1 = ld4nt(vr + 4);
    float sc = head_score(qa, qb, k0, k1);
    if (mask_lds[n]) sc = NEG_INF;      // exp -> 0
    upd(l, a0, a1, sc, v0, v1);
}

// Stream one attention layer: 2 chains per wave (nodes n, n+16 per iter),
// 15 unconditional pair iterations + uniform tail. Deposits per-wave partials.
__device__ __forceinline__ void stream_attn(
    const float4 qa, const float4 qb,
    const float* __restrict__ Kb, const float* __restrict__ Vb,
    const unsigned char* __restrict__ mask_lds,
    const int g, const int r,
    float* __restrict__ part_acc, float* __restrict__ part_l)
{
    float lA = 0.f, lB = 0.f;
    float4 aA0 = {0.f,0.f,0.f,0.f}, aA1 = {0.f,0.f,0.f,0.f};
    float4 aB0 = {0.f,0.f,0.f,0.f}, aB1 = {0.f,0.f,0.f,0.f};

    for (int i = 0; i < 15; ++i) {
        const int n = g + i * 32;
        do_node(qa, qb, Kb, Vb, mask_lds, n,      r, lA, aA0, aA1);
        do_node(qa, qb, Kb, Vb, mask_lds, n + 16, r, lB, aB0, aB1);
    }
    // tail: nodes 480..495 (chain A, all waves), 496..499 (chain B, g<4)
    do_node(qa, qb, Kb, Vb, mask_lds, g + 480, r, lA, aA0, aA1);
    if (g < 4)                          // wave-uniform branch
        do_node(qa, qb, Kb, Vb, mask_lds, g + 496, r, lB, aB0, aB1);

    float4 o0, o1;
    o0.x = aA0.x + aB0.x;  o0.y = aA0.y + aB0.y;
    o0.z = aA0.z + aB0.z;  o0.w = aA0.w + aB0.w;
    o1.x = aA1.x + aB1.x;  o1.y = aA1.y + aB1.y;
    o1.z = aA1.z + aB1.z;  o1.w = aA1.w + aB1.w;

    *reinterpret_cast<float4*>(part_acc + g * D + r * 8)     = o0;
    *reinterpret_cast<float4*>(part_acc + g * D + r * 8 + 4) = o1;
    if ((r & 3) == 0)
        part_l[g * H + (r >> 2)] = lA + lB;
}

// coalesced GEMV: dst_lds[j] = sum_k a_lds[k] * Wt[k][j] + bias[j]
__device__ __forceinline__ void gemv(
    const float* __restrict__ a_lds, const float* __restrict__ Wt,
    const float* __restrict__ bias, float* __restrict__ dst_lds,
    float* __restrict__ gemv_part, const int t)
{
    const int j = t & 511;
    const int half = t >> 9;
    const float* Wp = Wt + (size_t)half * 256 * D + j;
    const float* a  = a_lds + half * 256;
    float acc = 0.f;
#pragma unroll 4
    for (int k = 0; k < 256; ++k)
        acc += a[k] * Wp[(size_t)k * D];
    gemv_part[half * D + j] = acc;
    __syncthreads();
    if (t < D) dst_lds[t] = gemv_part[t] + gemv_part[D + t] + bias[t];
    __syncthreads();
}

// ---------------------------------------------------------------------------
// Monolith: one block (1024 threads) carries batch b through all 3 layers.
// ---------------------------------------------------------------------------
__global__ __launch_bounds__(1024) void fused_all(
    const float* __restrict__ query,
    const float* __restrict__ Katt,
    const float* __restrict__ Vatt,
    const unsigned char* __restrict__ mask,
    const float* __restrict__ Wt0, const float* __restrict__ b0,
    const float* __restrict__ Wtf, const float* __restrict__ bf,
    float* __restrict__ out)
{
    __shared__ __align__(16) float part_acc[16 * D];   // 32 KB
    __shared__ float part_l[16 * H];
    __shared__ __align__(16) float out_lds[D];
    __shared__ __align__(16) float mid_lds[D];
    __shared__ __align__(16) float q_lds[D];
    __shared__ float gemv_part[2 * D];
    __shared__ unsigned char mask_lds[512];
    __shared__ float s_lds[NN];
    __shared__ float red[16];
    __shared__ float bm, bs;

    const int b = blockIdx.x;
    const int t = threadIdx.x;
    const int r = t & 63;     // lane: dims [r*8, r*8+8) ; head = r>>2
    const int g = t >> 6;     // wave id

    if (t < 512) mask_lds[t] = (t < NN) ? mask[(size_t)b * NN + t] : 0;

    const float* Kbase = Katt + (size_t)b * NN * KSTRIDE;
    const float* Vbase = Vatt + (size_t)b * NN * KSTRIDE;

    float4 qa = ld4(query + (size_t)b * D + r * 8);
    float4 qb = ld4(query + (size_t)b * D + r * 8 + 4);
    __syncthreads();

    // ======================= layers 0 and 1 =======================
#pragma unroll 1
    for (int layer = 0; layer < 2; ++layer) {
        stream_attn(qa, qb, Kbase + layer * 512, Vbase + layer * 512,
                    mask_lds, g, r, part_acc, part_l);
        __syncthreads();

        // combine 16 wave-partials (plain sums; no-max softmax)
        if (t < D) {
            const int hd = t >> 5;
            float ls = 0.f, o = 0.f;
#pragma unroll
            for (int g2 = 0; g2 < 16; ++g2) {
                ls += part_l[g2 * H + hd];
                o  += part_acc[g2 * D + t];
            }
            out_lds[t] = o / ls;
        }
        __syncthreads();

        if (layer == 0) {
            gemv(out_lds, Wt0, b0, q_lds, gemv_part, t);        // q1
        } else {
            gemv(out_lds, Wt0, b0, mid_lds, gemv_part, t);      // q2
            gemv(mid_lds, Wtf, bf, q_lds, gemv_part, t);        // q_final
        }

        qa = ld4(q_lds + r * 8);
        qb = ld4(q_lds + r * 8 + 4);
    }

    // ======================= final layer =======================
    {
        const int wv   = t >> 6;
        const int l    = t & 63;
        const int half = l >> 5;
        const int l32  = l & 31;

        const float* qpp = q_lds + l32 * 16;
        const float4 f0 = ld4(qpp);
        const float4 f1 = ld4(qpp + 4);
        const float4 f2 = ld4(qpp + 8);
        const float4 f3 = ld4(qpp + 12);

        const float* Kb2 = Kbase + 1024;

        for (int n = wv * 2 + half; n < NN; n += 32) {
            const float* kr = Kb2 + (size_t)n * KSTRIDE + l32 * 16;
            const float4 k0 = ld4nt(kr);
            const float4 k1 = ld4nt(kr + 4);
            const float4 k2 = ld4nt(kr + 8);
            const float4 k3 = ld4nt(kr + 12);
            float s = f0.x * k0.x + f0.y * k0.y + f0.z * k0.z + f0.w * k0.w
                    + f1.x * k1.x + f1.y * k1.y + f1.z * k1.z + f1.w * k1.w
                    + f2.x * k2.x + f2.y * k2.y + f2.z * k2.z + f2.w * k2.w
                    + f3.x * k3.x + f3.y * k3.y + f3.z * k3.z + f3.w * k3.w;
#pragma unroll
            for (int o = 1; o < 32; o <<= 1) s += __shfl_xor(s, o);
            if (l32 == 0) {
                float sc = 10.0f * tanhf(s * 0.044194173824159216f); // 10*tanh(s/sqrt(512))
                if (mask_lds[n]) sc = NEG_INF;
                s_lds[n] = sc;
            }
        }
        __syncthreads();

        // block softmax over 500
        const float v = (t < NN) ? s_lds[t] : -3.4e38f;
        float m = v;
#pragma unroll
        for (int o = 1; o < 64; o <<= 1) m = fmaxf(m, __shfl_xor(m, o));
        if (l == 0) red[wv] = m;
        __syncthreads();
        if (t == 0) {
            float mm = red[0];
#pragma unroll
            for (int i = 1; i < 16; ++i) mm = fmaxf(mm, red[i]);
            bm = mm;
        }
        __syncthreads();
        const float e = (t < NN) ? __expf(v - bm) : 0.f;
        float ssum = e;
#pragma unroll
        for (int o = 1; o < 64; o <<= 1) ssum += __shfl_xor(ssum, o);
        if (l == 0) red[wv] = ssum;
        __syncthreads();
        if (t == 0) {
            float s2 = 0.f;
#pragma unroll
            for (int i = 0; i < 16; ++i) s2 += red[i];
            bs = 1.0f / s2;
        }
        __syncthreads();
        if (t < NN)
            __builtin_nontemporal_store(e * bs, out + (size_t)b * NN + t);
    }
}

// ---------------------------------------------------------------------------
extern "C" void kernel_launch(void* const* d_in, const int* in_sizes, int n_in,
                              void* d_out, int out_size, void* d_ws, size_t ws_size,
                              hipStream_t stream) {
    const float* query = (const float*)d_in[0];
    const float* Katt  = (const float*)d_in[1];
    const float* Vatt  = (const float*)d_in[2];
    const unsigned char* mask = (const unsigned char*)d_in[3];
    const float* W0w = (const float*)d_in[4];
    const float* W0b = (const float*)d_in[5];
    const float* Wfw = (const float*)d_in[6];
    const float* Wfb = (const float*)d_in[7];

    float* out = (float*)d_out;
    float* ws  = (float*)d_ws;
    float* Wt0 = ws + WS_WT0;
    float* Wtf = ws + WS_WTF;

    prep_transpose<<<dim3(16, 16, 2), 256, 0, stream>>>(W0w, Wfw, Wt0, Wtf);
    fused_all<<<BSZ, 1024, 0, stream>>>(query, Katt, Vatt, mask,
                                        Wt0, W0b, Wtf, Wfb, out);
}

// Round 8
// 293.758 us; speedup vs baseline: 1.1880x; 1.0019x over previous
//
#include <hip/hip_runtime.h>
#include <cstdint>
#include <cstddef>

#define BSZ 256
#define NN 500
#define D 512
#define H 16
#define KSTRIDE 1536
#define NEG_INF -1000000000.0f

// ws layout (float offsets)
#define WS_WT0   0          // 512*512  W0^T
#define WS_WTF   262144     // 512*512  Wqf^T

typedef float f32x4 __attribute__((ext_vector_type(4)));

// ---------------------------------------------------------------------------
// Prep: transpose W0 and Wqf (z selects) so GEMV reads are coalesced.
// ---------------------------------------------------------------------------
__global__ __launch_bounds__(256) void prep_transpose(
    const float* __restrict__ W0, const float* __restrict__ Wqf,
    float* __restrict__ Wt0, float* __restrict__ Wtf)
{
    __shared__ float tile[32][33];
    const float* in = blockIdx.z ? Wqf : W0;
    float* out      = blockIdx.z ? Wtf : Wt0;
    const int bx = blockIdx.x * 32, by = blockIdx.y * 32;
    const int tx = threadIdx.x & 31, ty = threadIdx.x >> 5;
#pragma unroll
    for (int i = 0; i < 32; i += 8)
        tile[ty + i][tx] = in[(size_t)(by + ty + i) * D + bx + tx];
    __syncthreads();
#pragma unroll
    for (int i = 0; i < 32; i += 8)
        out[(size_t)(bx + ty + i) * D + by + tx] = tile[tx][ty + i];
}

// ---------------------------------------------------------------------------
// helpers
// ---------------------------------------------------------------------------
__device__ __forceinline__ float4 ld4(const float* p) {
    return *reinterpret_cast<const float4*>(p);
}
__device__ __forceinline__ float4 ld4nt(const float* p) {
    f32x4 v = __builtin_nontemporal_load(reinterpret_cast<const f32x4*>(p));
    return float4{v.x, v.y, v.z, v.w};
}

// score for one head (32 dims across 4 lanes), scaled by 1/sqrt(32)
__device__ __forceinline__ float head_score(const float4 qa, const float4 qb,
                                            const float4 k0, const float4 k1)
{
    float s = qa.x * k0.x + qa.y * k0.y + qa.z * k0.z + qa.w * k0.w
            + qb.x * k1.x + qb.y * k1.y + qb.z * k1.z + qb.w * k1.w;
    s += __shfl_xor(s, 1);
    s += __shfl_xor(s, 2);
    return s * 0.17677669529663687f;   // 1/sqrt(32)
}

// no-max online update: e = exp(sc); l += e; acc += e*v   (masked -> e = 0)
__device__ __forceinline__ void upd(float& l, float4& a0, float4& a1,
                                    const float sc, const float4 v0, const float4 v1)
{
    const float e = __expf(sc);
    l += e;
    a0.x += e * v0.x; a0.y += e * v0.y; a0.z += e * v0.z; a0.w += e * v0.w;
    a1.x += e * v1.x; a1.y += e * v1.y; a1.z += e * v1.z; a1.w += e * v1.w;
}

// single-node tail helper
__device__ __forceinline__ void do_node(
    const float4 qa, const float4 qb,
    const float* __restrict__ Kb, const float* __restrict__ Vb,
    const unsigned char* __restrict__ mask_lds,
    const int n, const int r,
    float& l, float4& a0, float4& a1)
{
    const float* kr = Kb + (size_t)n * KSTRIDE + r * 8;
    const float* vr = Vb + (size_t)n * KSTRIDE + r * 8;
    const float4 k0 = ld4nt(kr), k1 = ld4nt(kr + 4);
    const float4 v0 = ld4nt(vr), v1 = ld4nt(vr + 4);
    float sc = head_score(qa, qb, k0, k1);
    if (mask_lds[n]) sc = NEG_INF;      // exp -> 0
    upd(l, a0, a1, sc, v0, v1);
}

// Stream one attention layer: THREE independent chains per wave
// (nodes n, n+16, n+32 each iter; i-stride 48). 10 tri-iterations cover
// nodes 0..479 exactly; uniform tails cover 480..499. All 12 float4 loads
// of an iteration are issued before any consuming math (max loads in flight).
__device__ __forceinline__ void stream_attn(
    const float4 qa, const float4 qb,
    const float* __restrict__ Kb, const float* __restrict__ Vb,
    const unsigned char* __restrict__ mask_lds,
    const int g, const int r,
    float* __restrict__ part_acc, float* __restrict__ part_l)
{
    float lA = 0.f, lB = 0.f, lC = 0.f;
    float4 aA0 = {0.f,0.f,0.f,0.f}, aA1 = {0.f,0.f,0.f,0.f};
    float4 aB0 = {0.f,0.f,0.f,0.f}, aB1 = {0.f,0.f,0.f,0.f};
    float4 aC0 = {0.f,0.f,0.f,0.f}, aC1 = {0.f,0.f,0.f,0.f};

    for (int i = 0; i < 10; ++i) {
        const int nA = g + i * 48;
        const int nB = nA + 16;
        const int nC = nA + 32;
        const float* krA = Kb + (size_t)nA * KSTRIDE + r * 8;
        const float* vrA = Vb + (size_t)nA * KSTRIDE + r * 8;
        const float* krB = Kb + (size_t)nB * KSTRIDE + r * 8;
        const float* vrB = Vb + (size_t)nB * KSTRIDE + r * 8;
        const float* krC = Kb + (size_t)nC * KSTRIDE + r * 8;
        const float* vrC = Vb + (size_t)nC * KSTRIDE + r * 8;

        // ---- issue all 12 loads first ----
        const float4 kA0 = ld4nt(krA), kA1 = ld4nt(krA + 4);
        const float4 vA0 = ld4nt(vrA), vA1 = ld4nt(vrA + 4);
        const float4 kB0 = ld4nt(krB), kB1 = ld4nt(krB + 4);
        const float4 vB0 = ld4nt(vrB), vB1 = ld4nt(vrB + 4);
        const float4 kC0 = ld4nt(krC), kC1 = ld4nt(krC + 4);
        const float4 vC0 = ld4nt(vrC), vC1 = ld4nt(vrC + 4);

        // ---- then consume ----
        float scA = head_score(qa, qb, kA0, kA1);
        if (mask_lds[nA]) scA = NEG_INF;
        upd(lA, aA0, aA1, scA, vA0, vA1);

        float scB = head_score(qa, qb, kB0, kB1);
        if (mask_lds[nB]) scB = NEG_INF;
        upd(lB, aB0, aB1, scB, vB0, vB1);

        float scC = head_score(qa, qb, kC0, kC1);
        if (mask_lds[nC]) scC = NEG_INF;
        upd(lC, aC0, aC1, scC, vC0, vC1);
    }
    // tails: 480..495 (chain A, all waves), 496..499 (chain B, g<4)
    do_node(qa, qb, Kb, Vb, mask_lds, g + 480, r, lA, aA0, aA1);
    if (g < 4)                          // wave-uniform branch
        do_node(qa, qb, Kb, Vb, mask_lds, g + 496, r, lB, aB0, aB1);

    float4 o0, o1;
    o0.x = aA0.x + aB0.x + aC0.x;  o0.y = aA0.y + aB0.y + aC0.y;
    o0.z = aA0.z + aB0.z + aC0.z;  o0.w = aA0.w + aB0.w + aC0.w;
    o1.x = aA1.x + aB1.x + aC1.x;  o1.y = aA1.y + aB1.y + aC1.y;
    o1.z = aA1.z + aB1.z + aC1.z;  o1.w = aA1.w + aB1.w + aC1.w;

    *reinterpret_cast<float4*>(part_acc + g * D + r * 8)     = o0;
    *reinterpret_cast<float4*>(part_acc + g * D + r * 8 + 4) = o1;
    if ((r & 3) == 0)
        part_l[g * H + (r >> 2)] = lA + lB + lC;
}

// coalesced GEMV: dst_lds[j] = sum_k a_lds[k] * Wt[k][j] + bias[j]
__device__ __forceinline__ void gemv(
    const float* __restrict__ a_lds, const float* __restrict__ Wt,
    const float* __restrict__ bias, float* __restrict__ dst_lds,
    float* __restrict__ gemv_part, const int t)
{
    const int j = t & 511;
    const int half = t >> 9;
    const float* Wp = Wt + (size_t)half * 256 * D + j;
    const float* a  = a_lds + half * 256;
    float acc = 0.f;
#pragma unroll 4
    for (int k = 0; k < 256; ++k)
        acc += a[k] * Wp[(size_t)k * D];
    gemv_part[half * D + j] = acc;
    __syncthreads();
    if (t < D) dst_lds[t] = gemv_part[t] + gemv_part[D + t] + bias[t];
    __syncthreads();
}

// ---------------------------------------------------------------------------
// Monolith: one block (1024 threads) carries batch b through all 3 layers.
// ---------------------------------------------------------------------------
__global__ __launch_bounds__(1024) void fused_all(
    const float* __restrict__ query,
    const float* __restrict__ Katt,
    const float* __restrict__ Vatt,
    const unsigned char* __restrict__ mask,
    const float* __restrict__ Wt0, const float* __restrict__ b0,
    const float* __restrict__ Wtf, const float* __restrict__ bf,
    float* __restrict__ out)
{
    __shared__ __align__(16) float part_acc[16 * D];   // 32 KB
    __shared__ float part_l[16 * H];
    __shared__ __align__(16) float out_lds[D];
    __shared__ __align__(16) float mid_lds[D];
    __shared__ __align__(16) float q_lds[D];
    __shared__ float gemv_part[2 * D];
    __shared__ unsigned char mask_lds[512];
    __shared__ float s_lds[NN];
    __shared__ float red[16];
    __shared__ float bm, bs;

    const int b = blockIdx.x;
    const int t = threadIdx.x;
    const int r = t & 63;     // lane: dims [r*8, r*8+8) ; head = r>>2
    const int g = t >> 6;     // wave id

    if (t < 512) mask_lds[t] = (t < NN) ? mask[(size_t)b * NN + t] : 0;

    const float* Kbase = Katt + (size_t)b * NN * KSTRIDE;
    const float* Vbase = Vatt + (size_t)b * NN * KSTRIDE;

    float4 qa = ld4(query + (size_t)b * D + r * 8);
    float4 qb = ld4(query + (size_t)b * D + r * 8 + 4);
    __syncthreads();

    // ======================= layers 0 and 1 =======================
#pragma unroll 1
    for (int layer = 0; layer < 2; ++layer) {
        stream_attn(qa, qb, Kbase + layer * 512, Vbase + layer * 512,
                    mask_lds, g, r, part_acc, part_l);
        __syncthreads();

        // combine 16 wave-partials (plain sums; no-max softmax)
        if (t < D) {
            const int hd = t >> 5;
            float ls = 0.f, o = 0.f;
#pragma unroll
            for (int g2 = 0; g2 < 16; ++g2) {
                ls += part_l[g2 * H + hd];
                o  += part_acc[g2 * D + t];
            }
            out_lds[t] = o / ls;
        }
        __syncthreads();

        if (layer == 0) {
            gemv(out_lds, Wt0, b0, q_lds, gemv_part, t);        // q1
        } else {
            gemv(out_lds, Wt0, b0, mid_lds, gemv_part, t);      // q2
            gemv(mid_lds, Wtf, bf, q_lds, gemv_part, t);        // q_final
        }

        qa = ld4(q_lds + r * 8);
        qb = ld4(q_lds + r * 8 + 4);
    }

    // ======================= final layer =======================
    {
        const int wv   = t >> 6;
        const int l    = t & 63;
        const int half = l >> 5;
        const int l32  = l & 31;

        const float* qpp = q_lds + l32 * 16;
        const float4 f0 = ld4(qpp);
        const float4 f1 = ld4(qpp + 4);
        const float4 f2 = ld4(qpp + 8);
        const float4 f3 = ld4(qpp + 12);

        const float* Kb2 = Kbase + 1024;

        for (int n = wv * 2 + half; n < NN; n += 32) {
            const float* kr = Kb2 + (size_t)n * KSTRIDE + l32 * 16;
            const float4 k0 = ld4nt(kr);
            const float4 k1 = ld4nt(kr + 4);
            const float4 k2 = ld4nt(kr + 8);
            const float4 k3 = ld4nt(kr + 12);
            float s = f0.x * k0.x + f0.y * k0.y + f0.z * k0.z + f0.w * k0.w
                    + f1.x * k1.x + f1.y * k1.y + f1.z * k1.z + f1.w * k1.w
                    + f2.x * k2.x + f2.y * k2.y + f2.z * k2.z + f2.w * k2.w
                    + f3.x * k3.x + f3.y * k3.y + f3.z * k3.z + f3.w * k3.w;
#pragma unroll
            for (int o = 1; o < 32; o <<= 1) s += __shfl_xor(s, o);
            if (l32 == 0) {
                float sc = 10.0f * tanhf(s * 0.044194173824159216f); // 10*tanh(s/sqrt(512))
                if (mask_lds[n]) sc = NEG_INF;
                s_lds[n] = sc;
            }
        }
        __syncthreads();

        // block softmax over 500
        const float v = (t < NN) ? s_lds[t] : -3.4e38f;
        float m = v;
#pragma unroll
        for (int o = 1; o < 64; o <<= 1) m = fmaxf(m, __shfl_xor(m, o));
        if (l == 0) red[wv] = m;
        __syncthreads();
        if (t == 0) {
            float mm = red[0];
#pragma unroll
            for (int i = 1; i < 16; ++i) mm = fmaxf(mm, red[i]);
            bm = mm;
        }
        __syncthreads();
        const float e = (t < NN) ? __expf(v - bm) : 0.f;
        float ssum = e;
#pragma unroll
        for (int o = 1; o < 64; o <<= 1) ssum += __shfl_xor(ssum, o);
        if (l == 0) red[wv] = ssum;
        __syncthreads();
        if (t == 0) {
            float s2 = 0.f;
#pragma unroll
            for (int i = 0; i < 16; ++i) s2 += red[i];
            bs = 1.0f / s2;
        }
        __syncthreads();
        if (t < NN)
            __builtin_nontemporal_store(e * bs, out + (size_t)b * NN + t);
    }
}

// ---------------------------------------------------------------------------
extern "C" void kernel_launch(void* const* d_in, const int* in_sizes, int n_in,
                              void* d_out, int out_size, void* d_ws, size_t ws_size,
                              hipStream_t stream) {
    const float* query = (const float*)d_in[0];
    const float* Katt  = (const float*)d_in[1];
    const float* Vatt  = (const float*)d_in[2];
    const unsigned char* mask = (const unsigned char*)d_in[3];
    const float* W0w = (const float*)d_in[4];
    const float* W0b = (const float*)d_in[5];
    const float* Wfw = (const float*)d_in[6];
    const float* Wfb = (const float*)d_in[7];

    float* out = (float*)d_out;
    float* ws  = (float*)d_ws;
    float* Wt0 = ws + WS_WT0;
    float* Wtf = ws + WS_WTF;

    prep_transpose<<<dim3(16, 16, 2), 256, 0, stream>>>(W0w, Wfw, Wt0, Wtf);
    fused_all<<<BSZ, 1024, 0, stream>>>(query, Katt, Vatt, mask,
                                        Wt0, W0b, Wtf, Wfb, out);
}